// Round 1
// baseline (314.712 us; speedup 1.0000x reference)
//
#include <hip/hip_runtime.h>

typedef short bf16x8 __attribute__((ext_vector_type(8)));
typedef float f32x4 __attribute__((ext_vector_type(4)));

__device__ __forceinline__ unsigned short f2b(float f) {
    unsigned int u = __builtin_bit_cast(unsigned int, f);
    unsigned int r = u + 0x7FFFu + ((u >> 16) & 1u);
    return (unsigned short)(r >> 16);
}

// ---------------------------------------------------------------------------
// K0: convert/reorder weights to bf16 in ws.
// ws bf16 layout (ushort idx): [0]=W1b(256x256) [65536]=Wkvb(512x256: k rows then v rows)
//                              [196608]=W3b(256x256: gate_road_w[:, :256])
__global__ __launch_bounds__(256) void k_prep(const float* __restrict__ w1,
                                              const float* __restrict__ wqkv,
                                              const float* __restrict__ w3,
                                              unsigned short* __restrict__ wsb) {
    int i = blockIdx.x * 256 + threadIdx.x;   // 65536 total
    int o = i >> 8, k = i & 255;
    wsb[i]           = f2b(w1[i]);                         // road_proj_w
    wsb[65536 + i]   = f2b(wqkv[(3 * o + 1) * 256 + k]);   // k rows
    wsb[131072 + i]  = f2b(wqkv[(3 * o + 2) * 256 + k]);   // v rows
    wsb[196608 + i]  = f2b(w3[o * 512 + k]);               // gate_road_w first half
}

// ---------------------------------------------------------------------------
// K1: tiny vector chains: ext_p -> eqkv -> (ext_q, ext_v) -> road_vec -> rg_const
__global__ __launch_bounds__(256) void k_tiny(const float* __restrict__ ext_context,
                                              const float* __restrict__ ext_proj_w,
                                              const float* __restrict__ ext_proj_b,
                                              const float* __restrict__ ext_qkv_w,
                                              const float* __restrict__ ext_qkv_b,
                                              const float* __restrict__ road_out_w,
                                              const float* __restrict__ road_out_b,
                                              const float* __restrict__ gate_road_w,
                                              const float* __restrict__ gate_road_b,
                                              float* __restrict__ ext_q,
                                              float* __restrict__ road_vec,
                                              float* __restrict__ rg_const) {
    int b = blockIdx.x, c = threadIdx.x;
    __shared__ float ctx[64], extp[256], extv[256], rv[256];
    if (c < 64) ctx[c] = ext_context[b * 64 + c];
    __syncthreads();
    float s = ext_proj_b[c];
    #pragma unroll 4
    for (int k = 0; k < 64; k++) s += ext_proj_w[c * 64 + k] * ctx[k];
    extp[c] = s;
    __syncthreads();
    float q = ext_qkv_b[c], v = ext_qkv_b[512 + c];
    #pragma unroll 4
    for (int k = 0; k < 256; k++) {
        float p = extp[k];
        q += ext_qkv_w[c * 256 + k] * p;
        v += ext_qkv_w[(512 + c) * 256 + k] * p;
    }
    ext_q[b * 256 + c] = q;
    extv[c] = v;
    __syncthreads();
    float r = road_out_b[c];
    #pragma unroll 4
    for (int k = 0; k < 256; k++) r += road_out_w[c * 256 + k] * extv[k];
    road_vec[b * 256 + c] = r;
    rv[c] = r;
    __syncthreads();
    float g = gate_road_b[c];
    #pragma unroll 4
    for (int k = 0; k < 256; k++) g += gate_road_w[c * 512 + 256 + k] * rv[k];
    rg_const[b * 256 + c] = g;
}

// ---------------------------------------------------------------------------
// K_mean: mean of low over spatial per (b,c). grid 2048 blocks.
__global__ __launch_bounds__(256) void k_mean(const float* __restrict__ low,
                                              float* __restrict__ mean_low) {
    int bc = blockIdx.x, t = threadIdx.x;
    const f32x4* p4 = (const f32x4*)(low + (size_t)bc * 4096);
    float s = 0.f;
    for (int i = t; i < 1024; i += 256) {
        f32x4 v = p4[i];
        s += v[0] + v[1] + v[2] + v[3];
    }
    for (int m = 32; m; m >>= 1) s += __shfl_xor(s, m, 64);
    __shared__ float red[4];
    if ((t & 63) == 0) red[t >> 6] = s;
    __syncthreads();
    if (t == 0) mean_low[bc] = (red[0] + red[1] + red[2] + red[3]) * (1.0f / 4096.0f);
}

// ---------------------------------------------------------------------------
// K2: per 64-pixel tile: X -> P (road_p) -> [K: scores in-register | V: to d_out]
// block 512 threads (8 waves as 2 wm x 4 wn). grid = 8 b * 64 tiles = 512.
__global__ __launch_bounds__(512) void k_gemm(const float* __restrict__ road_feat,
                                              const unsigned short* __restrict__ wsb,
                                              const float* __restrict__ b1,
                                              const float* __restrict__ bqkv,
                                              const float* __restrict__ extq,
                                              float* __restrict__ scores,
                                              float* __restrict__ V) {
    __shared__ unsigned short Xs[64 * 256];   // bf16, rows=pixels(64), cols=channels(256), swizzled
    __shared__ unsigned short Ps[64 * 256];
    const unsigned short* W1b  = wsb;
    const unsigned short* Wkvb = wsb + 65536;
    int b  = blockIdx.x >> 6;
    int p0 = (blockIdx.x & 63) << 6;
    int t  = threadIdx.x;
    const float* rfb = road_feat + (size_t)b * 1048576;

    // stage X tile (transpose to pixel-major, bf16, swizzled)
    for (int it = 0; it < 8; ++it) {
        int c  = (t >> 4) + it * 32;
        int j4 = (t & 15) * 4;
        f32x4 g = *(const f32x4*)(rfb + (size_t)c * 4096 + p0 + j4);
        #pragma unroll
        for (int i = 0; i < 4; i++) {
            int j = j4 + i;
            Xs[((j * 512 + 2 * c) ^ ((j & 15) << 4)) >> 1] = f2b(g[i]);
        }
    }
    __syncthreads();

    int w = t >> 6, lane = t & 63, l15 = lane & 15, lhi = lane >> 4;
    int wm = w >> 2, wn = w & 3;

    // ---- P phase: P[64][256] = X * W1^T, wave tile 32 x 64
    f32x4 accP[2][4] = {};
    for (int kk = 0; kk < 8; kk++) {
        bf16x8 a[2];
        #pragma unroll
        for (int mi = 0; mi < 2; mi++) {
            int j = wm * 32 + mi * 16 + l15;
            int off = (j * 512 + (kk * 32 + 8 * lhi) * 2) ^ ((j & 15) << 4);
            a[mi] = *(const bf16x8*)((const char*)Xs + off);
        }
        #pragma unroll
        for (int ni = 0; ni < 4; ni++) {
            int o = wn * 64 + ni * 16 + l15;
            bf16x8 bf = *(const bf16x8*)(W1b + o * 256 + kk * 32 + 8 * lhi);
            accP[0][ni] = __builtin_amdgcn_mfma_f32_16x16x32_bf16(a[0], bf, accP[0][ni], 0, 0, 0);
            accP[1][ni] = __builtin_amdgcn_mfma_f32_16x16x32_bf16(a[1], bf, accP[1][ni], 0, 0, 0);
        }
    }
    // bias + store P as bf16 (swizzled)
    #pragma unroll
    for (int ni = 0; ni < 4; ni++) {
        int o = wn * 64 + ni * 16 + l15;
        float bias = b1[o];
        #pragma unroll
        for (int mi = 0; mi < 2; mi++)
            #pragma unroll
            for (int r = 0; r < 4; r++) {
                int j = wm * 32 + mi * 16 + 4 * lhi + r;
                Ps[((j * 512 + 2 * o) ^ ((j & 15) << 4)) >> 1] = f2b(accP[mi][ni][r] + bias);
            }
    }
    __syncthreads();

    // ---- KV phase: KV[64][512] = P * Wkv^T, wave tile 32 x 128
    f32x4 acc[2][8] = {};
    for (int kk = 0; kk < 8; kk++) {
        bf16x8 a[2];
        #pragma unroll
        for (int mi = 0; mi < 2; mi++) {
            int j = wm * 32 + mi * 16 + l15;
            int off = (j * 512 + (kk * 32 + 8 * lhi) * 2) ^ ((j & 15) << 4);
            a[mi] = *(const bf16x8*)((const char*)Ps + off);
        }
        #pragma unroll
        for (int ni = 0; ni < 8; ni++) {
            int n = wn * 128 + ni * 16 + l15;
            bf16x8 bf = *(const bf16x8*)(Wkvb + n * 256 + kk * 32 + 8 * lhi);
            acc[0][ni] = __builtin_amdgcn_mfma_f32_16x16x32_bf16(a[0], bf, acc[0][ni], 0, 0, 0);
            acc[1][ni] = __builtin_amdgcn_mfma_f32_16x16x32_bf16(a[1], bf, acc[1][ni], 0, 0, 0);
        }
    }

    if (wn < 2) {
        // K channels c in [wn*128, wn*128+128): compute scores = (q . k) * scale
        float qA[4], qB[4], bk[8];
        #pragma unroll
        for (int hl = 0; hl < 4; ++hl) {
            int hg = wn * 4 + hl;
            qA[hl] = extq[b * 256 + hg * 32 + l15];
            qB[hl] = extq[b * 256 + hg * 32 + 16 + l15];
        }
        #pragma unroll
        for (int ni = 0; ni < 8; ni++) bk[ni] = bqkv[3 * (wn * 128 + ni * 16 + l15) + 1];
        #pragma unroll
        for (int mi = 0; mi < 2; mi++)
            #pragma unroll
            for (int r = 0; r < 4; r++) {
                int j = wm * 32 + mi * 16 + 4 * lhi + r;
                #pragma unroll
                for (int hl = 0; hl < 4; hl++) {
                    float s = (acc[mi][2 * hl][r] + bk[2 * hl]) * qA[hl]
                            + (acc[mi][2 * hl + 1][r] + bk[2 * hl + 1]) * qB[hl];
                    s += __shfl_xor(s, 1, 64);
                    s += __shfl_xor(s, 2, 64);
                    s += __shfl_xor(s, 4, 64);
                    s += __shfl_xor(s, 8, 64);
                    if (l15 == 0) {
                        int hg = wn * 4 + hl;
                        scores[(size_t)(b * 8 + hg) * 4096 + p0 + j] = s * 0.17677669529663687f;
                    }
                }
            }
    } else {
        // V channels cv in [(wn-2)*128, +128): write V[b][n][p][d] f32
        #pragma unroll
        for (int ni = 0; ni < 8; ni++) {
            int cv = (wn - 2) * 128 + ni * 16 + l15;
            float bv = bqkv[3 * cv + 2];
            int n = cv >> 5, d = cv & 31;
            float* vb = V + (size_t)(b * 8 + n) * 131072 + d;
            #pragma unroll
            for (int mi = 0; mi < 2; mi++)
                #pragma unroll
                for (int r = 0; r < 4; r++) {
                    int j = wm * 32 + mi * 16 + 4 * lhi + r;
                    vb[(size_t)(p0 + j) * 32] = acc[mi][ni][r] + bv;
                }
        }
    }
}

// ---------------------------------------------------------------------------
// K3: per (b,n): softmax over 4096 scores, then ext_head = attn @ V. 64 blocks.
__global__ __launch_bounds__(256) void k_attn(const float* __restrict__ scores,
                                              const float* __restrict__ V,
                                              float* __restrict__ ext_head) {
    int bn = blockIdx.x, t = threadIdx.x;
    const float* sc = scores + (size_t)bn * 4096;
    __shared__ float wls[4096];
    __shared__ float red[4];
    __shared__ float stot[2];
    float mx = -1e30f;
    for (int p = t; p < 4096; p += 256) mx = fmaxf(mx, sc[p]);
    for (int m = 32; m; m >>= 1) mx = fmaxf(mx, __shfl_xor(mx, m, 64));
    if ((t & 63) == 0) red[t >> 6] = mx;
    __syncthreads();
    if (t == 0) stot[0] = fmaxf(fmaxf(red[0], red[1]), fmaxf(red[2], red[3]));
    __syncthreads();
    mx = stot[0];
    float s = 0.f;
    for (int p = t; p < 4096; p += 256) {
        float e = expf(sc[p] - mx);
        wls[p] = e;
        s += e;
    }
    for (int m = 32; m; m >>= 1) s += __shfl_xor(s, m, 64);
    __syncthreads();   // red reuse
    if ((t & 63) == 0) red[t >> 6] = s;
    __syncthreads();
    if (t == 0) stot[1] = red[0] + red[1] + red[2] + red[3];
    __syncthreads();
    float inv = 1.0f / stot[1];
    int d = t & 31, pg = t >> 5;
    const float* vp = V + (size_t)bn * 131072;
    float acc = 0.f;
    for (int p = pg; p < 4096; p += 8) acc += wls[p] * vp[(size_t)p * 32 + d];
    __shared__ float part[8][33];
    part[pg][d] = acc;
    __syncthreads();
    if (t < 32) {
        float a = 0.f;
        #pragma unroll
        for (int g = 0; g < 8; g++) a += part[g][t];
        ext_head[bn * 32 + t] = a * inv;
    }
}

// ---------------------------------------------------------------------------
// K4: ext_vec = W_out @ ext_head + b ; ext_gate = sigmoid(W_ge @ [mean_low, ext_vec] + b)
__global__ __launch_bounds__(256) void k_vec(const float* __restrict__ ext_head,
                                             const float* __restrict__ ext_out_w,
                                             const float* __restrict__ ext_out_b,
                                             const float* __restrict__ mean_low,
                                             const float* __restrict__ gate_ext_w,
                                             const float* __restrict__ gate_ext_b,
                                             float* __restrict__ ext_vec,
                                             float* __restrict__ ext_gate) {
    int b = blockIdx.x, c = threadIdx.x;
    __shared__ float hd_[256], ev[256], ml[256];
    hd_[c] = ext_head[b * 256 + c];
    ml[c]  = mean_low[b * 256 + c];
    __syncthreads();
    float s = ext_out_b[c];
    #pragma unroll 4
    for (int k = 0; k < 256; k++) s += ext_out_w[c * 256 + k] * hd_[k];
    ext_vec[b * 256 + c] = s;
    ev[c] = s;
    __syncthreads();
    float z = gate_ext_b[c];
    #pragma unroll 4
    for (int k = 0; k < 256; k++)
        z += gate_ext_w[c * 512 + k] * ml[k] + gate_ext_w[c * 512 + 256 + k] * ev[k];
    ext_gate[b * 256 + c] = 1.0f / (1.0f + expf(-z));
}

// ---------------------------------------------------------------------------
// K5: ext_final = low + g*(v - low), g,v per (b,c). grid 2048 x 256, 4 float4 each.
__global__ __launch_bounds__(256) void k_ext_final(const float* __restrict__ low,
                                                   const float* __restrict__ ext_vec,
                                                   const float* __restrict__ ext_gate,
                                                   float* __restrict__ out) {
    int idx = blockIdx.x * 256 + threadIdx.x;
    #pragma unroll
    for (int rep = 0; rep < 4; ++rep) {
        int i = idx + rep * 524288;          // float4 index < 2097152
        int bc = i >> 10;
        float g = ext_gate[bc];
        float vv = ext_vec[bc];
        f32x4 L = *(const f32x4*)(low + (size_t)i * 4);
        f32x4 o;
        #pragma unroll
        for (int c = 0; c < 4; c++) o[c] = L[c] + g * (vv - L[c]);
        *(f32x4*)(out + (size_t)i * 4) = o;
    }
}

// ---------------------------------------------------------------------------
// K6: road gate GEMM + elementwise. f32 LDS tile (exact high for elementwise),
// bf16 fragments built on the fly. Writes road_final half of d_out.
__global__ __launch_bounds__(512) void k_road(const float* __restrict__ high,
                                              const unsigned short* __restrict__ W3b,
                                              const float* __restrict__ rg_const,
                                              const float* __restrict__ road_vec,
                                              float* __restrict__ outbuf) {
    __shared__ float Xs[64 * 256];   // f32, swizzled, rows=pixels cols=channels
    char* Xc = (char*)Xs;
    int b  = blockIdx.x >> 6;
    int p0 = (blockIdx.x & 63) << 6;
    int t  = threadIdx.x;
    const float* hb = high + (size_t)b * 1048576;

    for (int it = 0; it < 8; ++it) {
        int c  = (t >> 4) + it * 32;
        int j4 = (t & 15) * 4;
        f32x4 g = *(const f32x4*)(hb + (size_t)c * 4096 + p0 + j4);
        #pragma unroll
        for (int i = 0; i < 4; i++) {
            int j = j4 + i;
            *(float*)(Xc + ((j * 1024 + 4 * c) ^ ((j & 15) << 4))) = g[i];
        }
    }
    __syncthreads();

    int w = t >> 6, lane = t & 63, l15 = lane & 15, lhi = lane >> 4;
    int wm = w >> 2, wn = w & 3;
    f32x4 acc[2][4] = {};
    for (int kk = 0; kk < 8; kk++) {
        bf16x8 a[2];
        #pragma unroll
        for (int mi = 0; mi < 2; mi++) {
            int j = wm * 32 + mi * 16 + l15;
            int base = j * 1024 + (kk * 32 + 8 * lhi) * 4;
            int sw = (j & 15) << 4;
            f32x4 x0 = *(const f32x4*)(Xc + (base ^ sw));
            f32x4 x1 = *(const f32x4*)(Xc + ((base + 16) ^ sw));
            bf16x8 av;
            #pragma unroll
            for (int i = 0; i < 4; i++) {
                av[i]     = (short)f2b(x0[i]);
                av[4 + i] = (short)f2b(x1[i]);
            }
            a[mi] = av;
        }
        #pragma unroll
        for (int ni = 0; ni < 4; ni++) {
            int o = wn * 64 + ni * 16 + l15;
            bf16x8 bf = *(const bf16x8*)(W3b + o * 256 + kk * 32 + 8 * lhi);
            acc[0][ni] = __builtin_amdgcn_mfma_f32_16x16x32_bf16(a[0], bf, acc[0][ni], 0, 0, 0);
            acc[1][ni] = __builtin_amdgcn_mfma_f32_16x16x32_bf16(a[1], bf, acc[1][ni], 0, 0, 0);
        }
    }
    __syncthreads();   // all frag reads done before in-place epilogue writes

    #pragma unroll
    for (int ni = 0; ni < 4; ni++) {
        int o = wn * 64 + ni * 16 + l15;
        float rc = rg_const[b * 256 + o];
        float rv = road_vec[b * 256 + o];
        #pragma unroll
        for (int mi = 0; mi < 2; mi++)
            #pragma unroll
            for (int r = 0; r < 4; r++) {
                int j = wm * 32 + mi * 16 + 4 * lhi + r;
                float* slot = (float*)(Xc + ((j * 1024 + 4 * o) ^ ((j & 15) << 4)));
                float z = acc[mi][ni][r] + rc;
                float gte = 1.0f / (1.0f + expf(-z));
                float hv = *slot;
                *slot = hv + gte * (rv - hv);   // each (j,o) owned by exactly one lane
            }
    }
    __syncthreads();

    float* ob = outbuf + 8388608 + (size_t)b * 1048576;
    for (int it = 0; it < 8; ++it) {
        int c  = (t >> 4) + it * 32;
        int j4 = (t & 15) * 4;
        f32x4 o4;
        #pragma unroll
        for (int i = 0; i < 4; i++) {
            int j = j4 + i;
            o4[i] = *(const float*)(Xc + ((j * 1024 + 4 * c) ^ ((j & 15) << 4)));
        }
        *(f32x4*)(ob + (size_t)c * 4096 + p0 + j4) = o4;
    }
}

// ---------------------------------------------------------------------------
extern "C" void kernel_launch(void* const* d_in, const int* in_sizes, int n_in,
                              void* d_out, int out_size, void* d_ws, size_t ws_size,
                              hipStream_t stream) {
    const float* low         = (const float*)d_in[0];
    const float* high        = (const float*)d_in[1];
    const float* ext_context = (const float*)d_in[2];
    const float* road_feat   = (const float*)d_in[3];
    const float* ext_proj_w  = (const float*)d_in[4];
    const float* ext_proj_b  = (const float*)d_in[5];
    const float* road_proj_w = (const float*)d_in[6];
    const float* road_proj_b = (const float*)d_in[7];
    const float* ext_qkv_w   = (const float*)d_in[8];
    const float* ext_qkv_b   = (const float*)d_in[9];
    const float* road_qkv_w  = (const float*)d_in[10];
    const float* road_qkv_b  = (const float*)d_in[11];
    const float* ext_out_w   = (const float*)d_in[12];
    const float* ext_out_b   = (const float*)d_in[13];
    const float* road_out_w  = (const float*)d_in[14];
    const float* road_out_b  = (const float*)d_in[15];
    const float* gate_ext_w  = (const float*)d_in[16];
    const float* gate_ext_b  = (const float*)d_in[17];
    const float* gate_road_w = (const float*)d_in[18];
    const float* gate_road_b = (const float*)d_in[19];

    float* out = (float*)d_out;
    unsigned short* wsb = (unsigned short*)d_ws;
    float* fw = (float*)((char*)d_ws + 524288);
    float* ext_q    = fw;
    float* road_vec = fw + 2048;
    float* rg_const = fw + 4096;
    float* ext_head = fw + 6144;
    float* ext_vec  = fw + 8192;
    float* ext_gate = fw + 10240;
    float* mean_low = fw + 12288;
    float* scores = out;             // ext half of d_out used as scratch, overwritten by K5
    float* V      = out + 8388608;   // road half used as scratch, overwritten by K6

    k_prep<<<256, 256, 0, stream>>>(road_proj_w, road_qkv_w, gate_road_w, wsb);
    k_tiny<<<8, 256, 0, stream>>>(ext_context, ext_proj_w, ext_proj_b, ext_qkv_w, ext_qkv_b,
                                  road_out_w, road_out_b, gate_road_w, gate_road_b,
                                  ext_q, road_vec, rg_const);
    k_mean<<<2048, 256, 0, stream>>>(low, mean_low);
    k_gemm<<<512, 512, 0, stream>>>(road_feat, wsb, road_proj_b, road_qkv_b, ext_q, scores, V);
    k_attn<<<64, 256, 0, stream>>>(scores, V, ext_head);
    k_vec<<<8, 256, 0, stream>>>(ext_head, ext_out_w, ext_out_b, mean_low,
                                 gate_ext_w, gate_ext_b, ext_vec, ext_gate);
    k_ext_final<<<2048, 256, 0, stream>>>(low, ext_vec, ext_gate, out);
    k_road<<<512, 512, 0, stream>>>(high, wsb + 196608, rg_const, road_vec, out);
}

// Round 3
// 197.090 us; speedup vs baseline: 1.5968x; 1.5968x over previous
//
#include <hip/hip_runtime.h>

typedef short bf16x8 __attribute__((ext_vector_type(8)));
typedef float f32x4 __attribute__((ext_vector_type(4)));

__device__ __forceinline__ unsigned short f2b(float f) {
    unsigned int u = __builtin_bit_cast(unsigned int, f);
    unsigned int r = u + 0x7FFFu + ((u >> 16) & 1u);
    return (unsigned short)(r >> 16);
}

// ---------------------------------------------------------------------------
// K0: convert/reorder weights to bf16 in ws.
__global__ __launch_bounds__(256) void k_prep(const float* __restrict__ w1,
                                              const float* __restrict__ wqkv,
                                              const float* __restrict__ w3,
                                              unsigned short* __restrict__ wsb) {
    int i = blockIdx.x * 256 + threadIdx.x;   // 65536 total
    int o = i >> 8, k = i & 255;
    wsb[i]           = f2b(w1[i]);                         // road_proj_w
    wsb[65536 + i]   = f2b(wqkv[(3 * o + 1) * 256 + k]);   // k rows
    wsb[131072 + i]  = f2b(wqkv[(3 * o + 2) * 256 + k]);   // v rows
    wsb[196608 + i]  = f2b(w3[o * 512 + k]);               // gate_road_w first half
}

// ---------------------------------------------------------------------------
// K1: tiny vector chains: ext_p -> eqkv -> (ext_q, ext_v) -> road_vec -> rg_const
__global__ __launch_bounds__(256) void k_tiny(const float* __restrict__ ext_context,
                                              const float* __restrict__ ext_proj_w,
                                              const float* __restrict__ ext_proj_b,
                                              const float* __restrict__ ext_qkv_w,
                                              const float* __restrict__ ext_qkv_b,
                                              const float* __restrict__ road_out_w,
                                              const float* __restrict__ road_out_b,
                                              const float* __restrict__ gate_road_w,
                                              const float* __restrict__ gate_road_b,
                                              float* __restrict__ ext_q,
                                              float* __restrict__ road_vec,
                                              float* __restrict__ rg_const) {
    int b = blockIdx.x, c = threadIdx.x;
    __shared__ float ctx[64], extp[256], extv[256], rv[256];
    if (c < 64) ctx[c] = ext_context[b * 64 + c];
    __syncthreads();
    float s = ext_proj_b[c];
    #pragma unroll 4
    for (int k = 0; k < 64; k++) s += ext_proj_w[c * 64 + k] * ctx[k];
    extp[c] = s;
    __syncthreads();
    float q = ext_qkv_b[c], v = ext_qkv_b[512 + c];
    #pragma unroll 4
    for (int k = 0; k < 256; k++) {
        float p = extp[k];
        q += ext_qkv_w[c * 256 + k] * p;
        v += ext_qkv_w[(512 + c) * 256 + k] * p;
    }
    ext_q[b * 256 + c] = q;
    extv[c] = v;
    __syncthreads();
    float r = road_out_b[c];
    #pragma unroll 4
    for (int k = 0; k < 256; k++) r += road_out_w[c * 256 + k] * extv[k];
    road_vec[b * 256 + c] = r;
    rv[c] = r;
    __syncthreads();
    float g = gate_road_b[c];
    #pragma unroll 4
    for (int k = 0; k < 256; k++) g += gate_road_w[c * 512 + 256 + k] * rv[k];
    rg_const[b * 256 + c] = g;
}

// ---------------------------------------------------------------------------
// K_mean: mean of low over spatial per (b,c). grid 2048 blocks.
__global__ __launch_bounds__(256) void k_mean(const float* __restrict__ low,
                                              float* __restrict__ mean_low) {
    int bc = blockIdx.x, t = threadIdx.x;
    const f32x4* p4 = (const f32x4*)(low + (size_t)bc * 4096);
    float s = 0.f;
    for (int i = t; i < 1024; i += 256) {
        f32x4 v = p4[i];
        s += v[0] + v[1] + v[2] + v[3];
    }
    for (int m = 32; m; m >>= 1) s += __shfl_xor(s, m, 64);
    __shared__ float red[4];
    if ((t & 63) == 0) red[t >> 6] = s;
    __syncthreads();
    if (t == 0) mean_low[bc] = (red[0] + red[1] + red[2] + red[3]) * (1.0f / 4096.0f);
}

// ---------------------------------------------------------------------------
// K2: per 64-pixel tile: X -> P (road_p) -> [K: scores in-register | V: to d_out]
__global__ __launch_bounds__(512) void k_gemm(const float* __restrict__ road_feat,
                                              const unsigned short* __restrict__ wsb,
                                              const float* __restrict__ b1,
                                              const float* __restrict__ bqkv,
                                              const float* __restrict__ extq,
                                              float* __restrict__ scores,
                                              float* __restrict__ V) {
    __shared__ unsigned short Xs[64 * 256];   // bf16, rows=pixels(64), cols=channels(256), swizzled
    __shared__ unsigned short Ps[64 * 256];
    const unsigned short* W1b  = wsb;
    const unsigned short* Wkvb = wsb + 65536;
    int b  = blockIdx.x >> 6;
    int p0 = (blockIdx.x & 63) << 6;
    int t  = threadIdx.x;
    const float* rfb = road_feat + (size_t)b * 1048576;

    for (int it = 0; it < 8; ++it) {
        int c  = (t >> 4) + it * 32;
        int j4 = (t & 15) * 4;
        f32x4 g = *(const f32x4*)(rfb + (size_t)c * 4096 + p0 + j4);
        #pragma unroll
        for (int i = 0; i < 4; i++) {
            int j = j4 + i;
            Xs[((j * 512 + 2 * c) ^ ((j & 15) << 4)) >> 1] = f2b(g[i]);
        }
    }
    __syncthreads();

    int w = t >> 6, lane = t & 63, l15 = lane & 15, lhi = lane >> 4;
    int wm = w >> 2, wn = w & 3;

    // ---- P phase
    f32x4 accP[2][4] = {};
    for (int kk = 0; kk < 8; kk++) {
        bf16x8 a[2];
        #pragma unroll
        for (int mi = 0; mi < 2; mi++) {
            int j = wm * 32 + mi * 16 + l15;
            int off = (j * 512 + (kk * 32 + 8 * lhi) * 2) ^ ((j & 15) << 4);
            a[mi] = *(const bf16x8*)((const char*)Xs + off);
        }
        #pragma unroll
        for (int ni = 0; ni < 4; ni++) {
            int o = wn * 64 + ni * 16 + l15;
            bf16x8 bf = *(const bf16x8*)(W1b + o * 256 + kk * 32 + 8 * lhi);
            accP[0][ni] = __builtin_amdgcn_mfma_f32_16x16x32_bf16(a[0], bf, accP[0][ni], 0, 0, 0);
            accP[1][ni] = __builtin_amdgcn_mfma_f32_16x16x32_bf16(a[1], bf, accP[1][ni], 0, 0, 0);
        }
    }
    #pragma unroll
    for (int ni = 0; ni < 4; ni++) {
        int o = wn * 64 + ni * 16 + l15;
        float bias = b1[o];
        #pragma unroll
        for (int mi = 0; mi < 2; mi++)
            #pragma unroll
            for (int r = 0; r < 4; r++) {
                int j = wm * 32 + mi * 16 + 4 * lhi + r;
                Ps[((j * 512 + 2 * o) ^ ((j & 15) << 4)) >> 1] = f2b(accP[mi][ni][r] + bias);
            }
    }
    __syncthreads();

    // ---- KV phase
    f32x4 acc[2][8] = {};
    for (int kk = 0; kk < 8; kk++) {
        bf16x8 a[2];
        #pragma unroll
        for (int mi = 0; mi < 2; mi++) {
            int j = wm * 32 + mi * 16 + l15;
            int off = (j * 512 + (kk * 32 + 8 * lhi) * 2) ^ ((j & 15) << 4);
            a[mi] = *(const bf16x8*)((const char*)Ps + off);
        }
        #pragma unroll
        for (int ni = 0; ni < 8; ni++) {
            int n = wn * 128 + ni * 16 + l15;
            bf16x8 bf = *(const bf16x8*)(Wkvb + n * 256 + kk * 32 + 8 * lhi);
            acc[0][ni] = __builtin_amdgcn_mfma_f32_16x16x32_bf16(a[0], bf, acc[0][ni], 0, 0, 0);
            acc[1][ni] = __builtin_amdgcn_mfma_f32_16x16x32_bf16(a[1], bf, acc[1][ni], 0, 0, 0);
        }
    }

    if (wn < 2) {
        float qA[4], qB[4], bk[8];
        #pragma unroll
        for (int hl = 0; hl < 4; ++hl) {
            int hg = wn * 4 + hl;
            qA[hl] = extq[b * 256 + hg * 32 + l15];
            qB[hl] = extq[b * 256 + hg * 32 + 16 + l15];
        }
        #pragma unroll
        for (int ni = 0; ni < 8; ni++) bk[ni] = bqkv[3 * (wn * 128 + ni * 16 + l15) + 1];
        #pragma unroll
        for (int mi = 0; mi < 2; mi++)
            #pragma unroll
            for (int r = 0; r < 4; r++) {
                int j = wm * 32 + mi * 16 + 4 * lhi + r;
                #pragma unroll
                for (int hl = 0; hl < 4; hl++) {
                    float s = (acc[mi][2 * hl][r] + bk[2 * hl]) * qA[hl]
                            + (acc[mi][2 * hl + 1][r] + bk[2 * hl + 1]) * qB[hl];
                    s += __shfl_xor(s, 1, 64);
                    s += __shfl_xor(s, 2, 64);
                    s += __shfl_xor(s, 4, 64);
                    s += __shfl_xor(s, 8, 64);
                    if (l15 == 0) {
                        int hg = wn * 4 + hl;
                        scores[(size_t)(b * 8 + hg) * 4096 + p0 + j] = s * 0.17677669529663687f;
                    }
                }
            }
    } else {
        #pragma unroll
        for (int ni = 0; ni < 8; ni++) {
            int cv = (wn - 2) * 128 + ni * 16 + l15;
            float bv = bqkv[3 * cv + 2];
            int n = cv >> 5, d = cv & 31;
            float* vb = V + (size_t)(b * 8 + n) * 131072 + d;
            #pragma unroll
            for (int mi = 0; mi < 2; mi++)
                #pragma unroll
                for (int r = 0; r < 4; r++) {
                    int j = wm * 32 + mi * 16 + 4 * lhi + r;
                    vb[(size_t)(p0 + j) * 32] = acc[mi][ni][r] + bv;
                }
        }
    }
}

// ---------------------------------------------------------------------------
// K3a: split-K attention pass 1. grid = 64 bn * 32 splits = 2048 blocks.
// Each block: 128 positions -> local max, local expsum, partial PV (32 d).
__global__ __launch_bounds__(256) void k_attn1(const float* __restrict__ scores,
                                               const float* __restrict__ V,
                                               float* __restrict__ pmax,
                                               float* __restrict__ psum,
                                               float* __restrict__ ppv) {
    int bn = blockIdx.x >> 5, sp = blockIdx.x & 31;
    int t = threadIdx.x;
    const float* sc = scores + (size_t)bn * 4096 + sp * 128;
    const float* vp = V + (size_t)bn * 131072 + (size_t)sp * 128 * 32;
    __shared__ float es[128];
    __shared__ float red[4];
    __shared__ float sm0;
    float s = (t < 128) ? sc[t] : -3e38f;
    float mx = s;
    for (int m = 32; m; m >>= 1) mx = fmaxf(mx, __shfl_xor(mx, m, 64));
    if ((t & 63) == 0) red[t >> 6] = mx;
    __syncthreads();
    if (t == 0) sm0 = fmaxf(fmaxf(red[0], red[1]), fmaxf(red[2], red[3]));
    __syncthreads();
    float gm = sm0;
    float e = (t < 128) ? expf(s - gm) : 0.f;
    if (t < 128) es[t] = e;
    float ssum = e;
    for (int m = 32; m; m >>= 1) ssum += __shfl_xor(ssum, m, 64);
    if ((t & 63) == 0) red[t >> 6] = ssum;
    __syncthreads();   // also makes es[] visible
    if (t == 0) {
        pmax[bn * 32 + sp] = gm;
        psum[bn * 32 + sp] = red[0] + red[1] + red[2] + red[3];
    }
    int d = t & 31, pg = t >> 5;   // 8 p-groups
    float acc = 0.f;
    #pragma unroll 4
    for (int i = 0; i < 16; i++) {
        int p = pg + 8 * i;
        acc += es[p] * vp[(size_t)p * 32 + d];
    }
    __shared__ float part[8][33];
    part[pg][d] = acc;
    __syncthreads();
    if (t < 32) {
        float a = 0.f;
        #pragma unroll
        for (int g = 0; g < 8; g++) a += part[g][t];
        ppv[(size_t)(bn * 32 + sp) * 32 + t] = a;
    }
}

// K3b: combine 32 splits per (b,n). 64 blocks x 64 threads.
__global__ __launch_bounds__(64) void k_attn2(const float* __restrict__ pmax,
                                              const float* __restrict__ psum,
                                              const float* __restrict__ ppv,
                                              float* __restrict__ ext_head) {
    int bn = blockIdx.x, t = threadIdx.x;
    __shared__ float wgt[32];
    __shared__ float stot;
    float lm = (t < 32) ? pmax[bn * 32 + t] : -3e38f;
    float gm = lm;
    for (int m = 16; m; m >>= 1) gm = fmaxf(gm, __shfl_xor(gm, m, 64));
    if (t < 32) {
        float w = expf(lm - gm);
        wgt[t] = w;
        float ws_ = w * psum[bn * 32 + t];
        for (int m = 16; m; m >>= 1) ws_ += __shfl_xor(ws_, m, 64);
        if (t == 0) stot = ws_;
    }
    __syncthreads();
    float inv = 1.0f / stot;
    int d = t & 31, h = t >> 5;
    float a = 0.f;
    #pragma unroll
    for (int s2 = h * 16; s2 < h * 16 + 16; s2++)
        a += wgt[s2] * ppv[(size_t)(bn * 32 + s2) * 32 + d];
    a += __shfl_xor(a, 32, 64);
    if (t < 32) ext_head[bn * 32 + d] = a * inv;
}

// ---------------------------------------------------------------------------
// K4: ext_vec / ext_gate
__global__ __launch_bounds__(256) void k_vec(const float* __restrict__ ext_head,
                                             const float* __restrict__ ext_out_w,
                                             const float* __restrict__ ext_out_b,
                                             const float* __restrict__ mean_low,
                                             const float* __restrict__ gate_ext_w,
                                             const float* __restrict__ gate_ext_b,
                                             float* __restrict__ ext_vec,
                                             float* __restrict__ ext_gate) {
    int b = blockIdx.x, c = threadIdx.x;
    __shared__ float hd_[256], ev[256], ml[256];
    hd_[c] = ext_head[b * 256 + c];
    ml[c]  = mean_low[b * 256 + c];
    __syncthreads();
    float s = ext_out_b[c];
    #pragma unroll 4
    for (int k = 0; k < 256; k++) s += ext_out_w[c * 256 + k] * hd_[k];
    ext_vec[b * 256 + c] = s;
    ev[c] = s;
    __syncthreads();
    float z = gate_ext_b[c];
    #pragma unroll 4
    for (int k = 0; k < 256; k++)
        z += gate_ext_w[c * 512 + k] * ml[k] + gate_ext_w[c * 512 + 256 + k] * ev[k];
    ext_gate[b * 256 + c] = 1.0f / (1.0f + expf(-z));
}

// ---------------------------------------------------------------------------
// K5: ext_final
__global__ __launch_bounds__(256) void k_ext_final(const float* __restrict__ low,
                                                   const float* __restrict__ ext_vec,
                                                   const float* __restrict__ ext_gate,
                                                   float* __restrict__ out) {
    int idx = blockIdx.x * 256 + threadIdx.x;
    #pragma unroll
    for (int rep = 0; rep < 4; ++rep) {
        int i = idx + rep * 524288;
        int bc = i >> 10;
        float g = ext_gate[bc];
        float vv = ext_vec[bc];
        f32x4 L = *(const f32x4*)(low + (size_t)i * 4);
        f32x4 o;
        #pragma unroll
        for (int c = 0; c < 4; c++) o[c] = L[c] + g * (vv - L[c]);
        *(f32x4*)(out + (size_t)i * 4) = o;
    }
}

// ---------------------------------------------------------------------------
// K6: road gate GEMM + elementwise.
__global__ __launch_bounds__(512) void k_road(const float* __restrict__ high,
                                              const unsigned short* __restrict__ W3b,
                                              const float* __restrict__ rg_const,
                                              const float* __restrict__ road_vec,
                                              float* __restrict__ outbuf) {
    __shared__ float Xs[64 * 256];
    char* Xc = (char*)Xs;
    int b  = blockIdx.x >> 6;
    int p0 = (blockIdx.x & 63) << 6;
    int t  = threadIdx.x;
    const float* hb = high + (size_t)b * 1048576;

    for (int it = 0; it < 8; ++it) {
        int c  = (t >> 4) + it * 32;
        int j4 = (t & 15) * 4;
        f32x4 g = *(const f32x4*)(hb + (size_t)c * 4096 + p0 + j4);
        #pragma unroll
        for (int i = 0; i < 4; i++) {
            int j = j4 + i;
            *(float*)(Xc + ((j * 1024 + 4 * c) ^ ((j & 15) << 4))) = g[i];
        }
    }
    __syncthreads();

    int w = t >> 6, lane = t & 63, l15 = lane & 15, lhi = lane >> 4;
    int wm = w >> 2, wn = w & 3;
    f32x4 acc[2][4] = {};
    for (int kk = 0; kk < 8; kk++) {
        bf16x8 a[2];
        #pragma unroll
        for (int mi = 0; mi < 2; mi++) {
            int j = wm * 32 + mi * 16 + l15;
            int base = j * 1024 + (kk * 32 + 8 * lhi) * 4;
            int sw = (j & 15) << 4;
            f32x4 x0 = *(const f32x4*)(Xc + (base ^ sw));
            f32x4 x1 = *(const f32x4*)(Xc + ((base + 16) ^ sw));
            bf16x8 av;
            #pragma unroll
            for (int i = 0; i < 4; i++) {
                av[i]     = (short)f2b(x0[i]);
                av[4 + i] = (short)f2b(x1[i]);
            }
            a[mi] = av;
        }
        #pragma unroll
        for (int ni = 0; ni < 4; ni++) {
            int o = wn * 64 + ni * 16 + l15;
            bf16x8 bf = *(const bf16x8*)(W3b + o * 256 + kk * 32 + 8 * lhi);
            acc[0][ni] = __builtin_amdgcn_mfma_f32_16x16x32_bf16(a[0], bf, acc[0][ni], 0, 0, 0);
            acc[1][ni] = __builtin_amdgcn_mfma_f32_16x16x32_bf16(a[1], bf, acc[1][ni], 0, 0, 0);
        }
    }
    __syncthreads();

    #pragma unroll
    for (int ni = 0; ni < 4; ni++) {
        int o = wn * 64 + ni * 16 + l15;
        float rc = rg_const[b * 256 + o];
        float rv = road_vec[b * 256 + o];
        #pragma unroll
        for (int mi = 0; mi < 2; mi++)
            #pragma unroll
            for (int r = 0; r < 4; r++) {
                int j = wm * 32 + mi * 16 + 4 * lhi + r;
                float* slot = (float*)(Xc + ((j * 1024 + 4 * o) ^ ((j & 15) << 4)));
                float z = acc[mi][ni][r] + rc;
                float gte = 1.0f / (1.0f + expf(-z));
                float hv = *slot;
                *slot = hv + gte * (rv - hv);
            }
    }
    __syncthreads();

    float* ob = outbuf + 8388608 + (size_t)b * 1048576;
    for (int it = 0; it < 8; ++it) {
        int c  = (t >> 4) + it * 32;
        int j4 = (t & 15) * 4;
        f32x4 o4;
        #pragma unroll
        for (int i = 0; i < 4; i++) {
            int j = j4 + i;
            o4[i] = *(const float*)(Xc + ((j * 1024 + 4 * c) ^ ((j & 15) << 4)));
        }
        *(f32x4*)(ob + (size_t)c * 4096 + p0 + j4) = o4;
    }
}

// ---------------------------------------------------------------------------
extern "C" void kernel_launch(void* const* d_in, const int* in_sizes, int n_in,
                              void* d_out, int out_size, void* d_ws, size_t ws_size,
                              hipStream_t stream) {
    const float* low         = (const float*)d_in[0];
    const float* high        = (const float*)d_in[1];
    const float* ext_context = (const float*)d_in[2];
    const float* road_feat   = (const float*)d_in[3];
    const float* ext_proj_w  = (const float*)d_in[4];
    const float* ext_proj_b  = (const float*)d_in[5];
    const float* road_proj_w = (const float*)d_in[6];
    const float* road_proj_b = (const float*)d_in[7];
    const float* ext_qkv_w   = (const float*)d_in[8];
    const float* ext_qkv_b   = (const float*)d_in[9];
    const float* road_qkv_w  = (const float*)d_in[10];
    const float* road_qkv_b  = (const float*)d_in[11];
    const float* ext_out_w   = (const float*)d_in[12];
    const float* ext_out_b   = (const float*)d_in[13];
    const float* road_out_w  = (const float*)d_in[14];
    const float* road_out_b  = (const float*)d_in[15];
    const float* gate_ext_w  = (const float*)d_in[16];
    const float* gate_ext_b  = (const float*)d_in[17];
    const float* gate_road_w = (const float*)d_in[18];
    const float* gate_road_b = (const float*)d_in[19];

    float* out = (float*)d_out;
    unsigned short* wsb = (unsigned short*)d_ws;
    float* fw = (float*)((char*)d_ws + 524288);
    float* ext_q    = fw;
    float* road_vec = fw + 2048;
    float* rg_const = fw + 4096;
    float* ext_head = fw + 6144;
    float* ext_vec  = fw + 8192;
    float* ext_gate = fw + 10240;
    float* mean_low = fw + 12288;
    float* scores = out;               // ext half [0, 1M floats) as scratch
    float* V      = out + 8388608;     // road half as scratch (V f32)
    // split-K partials live in dead space of the ext half (overwritten by K5):
    float* pmax = out + 2097152;
    float* psum = out + 2099200;
    float* ppv  = out + 2101248;       // 65536 floats

    k_prep<<<256, 256, 0, stream>>>(road_proj_w, road_qkv_w, gate_road_w, wsb);
    k_tiny<<<8, 256, 0, stream>>>(ext_context, ext_proj_w, ext_proj_b, ext_qkv_w, ext_qkv_b,
                                  road_out_w, road_out_b, gate_road_w, gate_road_b,
                                  ext_q, road_vec, rg_const);
    k_mean<<<2048, 256, 0, stream>>>(low, mean_low);
    k_gemm<<<512, 512, 0, stream>>>(road_feat, wsb, road_proj_b, road_qkv_b, ext_q, scores, V);
    k_attn1<<<2048, 256, 0, stream>>>(scores, V, pmax, psum, ppv);
    k_attn2<<<64, 64, 0, stream>>>(pmax, psum, ppv, ext_head);
    k_vec<<<8, 256, 0, stream>>>(ext_head, ext_out_w, ext_out_b, mean_low,
                                 gate_ext_w, gate_ext_b, ext_vec, ext_gate);
    k_ext_final<<<2048, 256, 0, stream>>>(low, ext_vec, ext_gate, out);
    k_road<<<512, 512, 0, stream>>>(high, wsb + 196608, rg_const, road_vec, out);
}